// Round 14
// baseline (161.233 us; speedup 1.0000x reference)
//
#include <hip/hip_runtime.h>
#include <hip/hip_bf16.h>
#include <math.h>

#define N_NODES 50000
#define N_EDGES 400000
#define IN_DIM 256
#define OUT_DIM 64
#define HEADS 2
#define ATTN_HIDDEN 64
#define ALPHA_SLOPE 0.2f
#define TEMP 0.55f
#define NHF 128   // HEADS*OUT_DIM
#define ZDIM 384  // Wh(128) | Us(128) | Ud(128)

typedef __bf16 bf16x8 __attribute__((ext_vector_type(8)));
typedef float f32x4 __attribute__((ext_vector_type(4)));

__device__ __forceinline__ ushort f2bf(float f) {
    unsigned u = __float_as_uint(f);
    u = (u + 0x7fffu + ((u >> 16) & 1u)) >> 16;
    return (ushort)u;
}
__device__ __forceinline__ unsigned pack2(float a, float b) {
    return (unsigned)f2bf(a) | ((unsigned)f2bf(b) << 16);
}
__device__ __forceinline__ float bfl(unsigned u) { return __uint_as_float(u << 16); }
__device__ __forceinline__ float bfh(unsigned u) { return __uint_as_float(u & 0xffff0000u); }

// ---------------------------------------------------------------------------
// K1: build Wctf (combined weights, MFMA B-fragment order) + seg[] in one
// launch. Fragment position for (n,k): c=n>>4, r16=n&15, kc=k>>5, q=(k>>3)&3,
// j=k&7 -> pos = ((c*8+kc)*64 + q*16 + r16)*8 + j. Each 4-c-tile group
// (64 cols) is a contiguous 32 KB half-slab.
// ---------------------------------------------------------------------------
__global__ __launch_bounds__(256) void k_combine(const float* __restrict__ W,
                                                 const float* __restrict__ Wa,
                                                 ushort* __restrict__ Wctf,
                                                 const int* __restrict__ dst,
                                                 int* __restrict__ seg) {
    __shared__ float col[64];
    const int b = blockIdx.x;
    const int t = threadIdx.x;
    if (b >= ZDIM) {   // segstart path
        int n = (b - ZDIM) * 256 + t;
        if (n > N_NODES) return;
        int lo = 0, hi = N_EDGES;
        while (lo < hi) {
            int mid = (lo + hi) >> 1;
            if (dst[mid] < n) lo = mid + 1; else hi = mid;
        }
        seg[n] = lo;
        return;
    }
    const int n = b;      // output column 0..383
    const int k = t;      // input dim 0..255
    const int c = n >> 4, r16 = n & 15;
    const int kc = k >> 5, q = (k >> 3) & 3, j = k & 7;
    const size_t pos = (size_t)(((c * 8 + kc) * 64 + q * 16 + r16)) * 8 + j;

    float val;
    if (n < 128) {
        val = W[(size_t)k * NHF + n];
    } else {
        const int part = (n - 128) >> 7;       // 0 = src-half, 1 = dst-half
        const int idx = (n - 128) & 127;
        const int h = idx >> 6;
        const int cc = idx & 63;
        const int fb = part ? 64 : 0;
        if (t < 64) col[t] = Wa[(size_t)h * 8192 + (size_t)(fb + t) * 64 + cc];
        __syncthreads();
        const float* wr = W + (size_t)k * NHF + h * 64;
        float acc = 0.f;
#pragma unroll
        for (int f = 0; f < 64; f++) acc += wr[f] * col[f];
        val = acc;
    }
    Wctf[pos] = f2bf(val);
}

// ---------------------------------------------------------------------------
// K2: Z[50000,384] = x @ Wcomb. Grid = 782 row-blocks; block = 4 waves x 16
// rows. A panel (8 uint4/lane) loaded ONCE — x fetched once from HBM. Block
// loops over SIX 32 KB half-slabs (4 c-tiles each): stage (2048 uint4,
// coalesced, lane-linear), barrier, barrier-free K-loop (32 ds_read_b128 +
// 32 MFMA per wave), barrier, next. 32 KB LDS + ~80 VGPR => 4 blocks/CU:
// the whole grid is co-resident, pure HBM/L2 stream.
// A frag: A[m=lane&15][k=(lane>>4)*8+j]; D: row=(lane>>4)*4+rr, col=lane&15.
// ---------------------------------------------------------------------------
__global__ __launch_bounds__(256, 4) void k_gemm(const float* __restrict__ x,
                                                 const ushort* __restrict__ Wctf,
                                                 ushort* __restrict__ Zb) {
    __shared__ __align__(16) ushort Bs[16384];   // 32 KB
    const int t = threadIdx.x;
    const int w = t >> 6, lane = t & 63;
    const int q = lane >> 4, r16 = lane & 15;
    const int rowbase = blockIdx.x * 64 + w * 16;    // wave's 16 rows

    // ---- stage half-slab 0 (2048 uint4 = 32 KB)
    {
        const uint4* gs = (const uint4*)Wctf;
        uint4* ls = (uint4*)Bs;
#pragma unroll
        for (int i = 0; i < 8; i++) ls[i * 256 + t] = gs[i * 256 + t];
    }

    // ---- prologue: load + pack the wave's ENTIRE A panel (read x ONCE)
    int rA = rowbase + r16;
    rA = rA < N_NODES ? rA : N_NODES - 1;
    const float* xp = x + (size_t)rA * IN_DIM + q * 8;
    uint4 Areg[8];
#pragma unroll
    for (int kc = 0; kc < 8; kc++) {
        const float4 a0 = *(const float4*)(xp + kc * 32);
        const float4 a1 = *(const float4*)(xp + kc * 32 + 4);
        Areg[kc].x = pack2(a0.x, a0.y); Areg[kc].y = pack2(a0.z, a0.w);
        Areg[kc].z = pack2(a1.x, a1.y); Areg[kc].w = pack2(a1.z, a1.w);
    }

    __syncthreads();   // half-slab 0 visible

#pragma unroll 1
    for (int s = 0; s < 6; s++) {
        f32x4 acc[4];
#pragma unroll
        for (int c = 0; c < 4; c++) acc[c] = (f32x4){0.f, 0.f, 0.f, 0.f};

        // K-loop: global-free, barrier-free, fully unrolled
#pragma unroll
        for (int kc = 0; kc < 8; kc++) {
            const bf16x8 af = *(const bf16x8*)&Areg[kc];
#pragma unroll
            for (int c = 0; c < 4; c++) {
                const bf16x8 bf = *(const bf16x8*)&Bs[((c * 8 + kc) * 64 + lane) * 8];
                acc[c] = __builtin_amdgcn_mfma_f32_16x16x32_bf16(af, bf, acc[c], 0, 0, 0);
            }
        }

        if (s < 5) {
            __syncthreads();   // everyone done reading half-slab s
            const uint4* gs = (const uint4*)Wctf + (size_t)(s + 1) * 2048;
            uint4* ls = (uint4*)Bs;
#pragma unroll
            for (int i = 0; i < 8; i++) ls[i * 256 + t] = gs[i * 256 + t];
        }

        // epilogue for half-slab s (c-tiles 4s..4s+3)
#pragma unroll
        for (int c = 0; c < 4; c++)
#pragma unroll
            for (int rr = 0; rr < 4; rr++) {
                const int row = rowbase + q * 4 + rr;
                if (row < N_NODES)
                    Zb[(size_t)row * ZDIM + (s * 4 + c) * 16 + r16] = f2bf(acc[c][rr]);
            }

        if (s < 5) __syncthreads();   // half-slab s+1 visible
    }
}

// ---------------------------------------------------------------------------
// K3: fused logits + online segment-softmax + weighted accumulate.
// 8 lanes per node (16 channels/lane), 8 nodes per wave, 32 nodes per block.
// Lane l8 owns channels 16*l8..16*l8+15 (l8<4: head0, l8>=4: head1).
// Per edge: 2x uint4 gather of Us[src] + 2x of Wh[src], 1-deep prefetch;
// logit reduce = 2 xor-shuffles over the 4-lane head halves; per-lane
// online (m,l); head-mean via final xor-4.
// ---------------------------------------------------------------------------
__global__ __launch_bounds__(256) void k_fused(const ushort* __restrict__ Zb,
                                               const float* __restrict__ avec,
                                               const int* __restrict__ src,
                                               const int* __restrict__ seg,
                                               float* __restrict__ out) {
    const int lane = threadIdx.x & 63;
    const int wv = threadIdx.x >> 6;
    const int g = lane >> 3, l8 = lane & 7;
    const int n = blockIdx.x * 32 + wv * 8 + g;
    if (n >= N_NODES) return;
    const int choff = 16 * l8;   // channel offset in the 128-channel block

    float a[16], ud[16];
#pragma unroll
    for (int i = 0; i < 4; i++) {
        const float4 av = *(const float4*)(avec + choff + 4 * i);
        a[4 * i] = av.x; a[4 * i + 1] = av.y; a[4 * i + 2] = av.z; a[4 * i + 3] = av.w;
    }
    {
        const uint4 u0 = *(const uint4*)(Zb + (size_t)n * ZDIM + 256 + choff);
        const uint4 u1 = *(const uint4*)(Zb + (size_t)n * ZDIM + 256 + choff + 8);
        ud[0] = bfl(u0.x); ud[1] = bfh(u0.x); ud[2] = bfl(u0.y); ud[3] = bfh(u0.y);
        ud[4] = bfl(u0.z); ud[5] = bfh(u0.z); ud[6] = bfl(u0.w); ud[7] = bfh(u0.w);
        ud[8] = bfl(u1.x); ud[9] = bfh(u1.x); ud[10] = bfl(u1.y); ud[11] = bfh(u1.y);
        ud[12] = bfl(u1.z); ud[13] = bfh(u1.z); ud[14] = bfl(u1.w); ud[15] = bfh(u1.w);
    }

    const int e0 = seg[n], e1 = seg[n + 1];
    float m = -INFINITY, l = 0.f;
    float acc[16];
#pragma unroll
    for (int j = 0; j < 16; j++) acc[j] = 0.f;

    uint4 us0 = make_uint4(0,0,0,0), us1 = us0, wh0 = us0, wh1 = us0;
    if (e0 < e1) {
        const int s = src[e0];
        us0 = *(const uint4*)(Zb + (size_t)s * ZDIM + 128 + choff);
        us1 = *(const uint4*)(Zb + (size_t)s * ZDIM + 128 + choff + 8);
        wh0 = *(const uint4*)(Zb + (size_t)s * ZDIM + choff);
        wh1 = *(const uint4*)(Zb + (size_t)s * ZDIM + choff + 8);
    }
    for (int e = e0; e < e1; e++) {
        const uint4 cu0 = us0, cu1 = us1, cw0 = wh0, cw1 = wh1;
        if (e + 1 < e1) {                 // prefetch next edge during reduce
            const int sn = src[e + 1];
            us0 = *(const uint4*)(Zb + (size_t)sn * ZDIM + 128 + choff);
            us1 = *(const uint4*)(Zb + (size_t)sn * ZDIM + 128 + choff + 8);
            wh0 = *(const uint4*)(Zb + (size_t)sn * ZDIM + choff);
            wh1 = *(const uint4*)(Zb + (size_t)sn * ZDIM + choff + 8);
        }
        float us[16];
        us[0] = bfl(cu0.x); us[1] = bfh(cu0.x); us[2] = bfl(cu0.y); us[3] = bfh(cu0.y);
        us[4] = bfl(cu0.z); us[5] = bfh(cu0.z); us[6] = bfl(cu0.w); us[7] = bfh(cu0.w);
        us[8] = bfl(cu1.x); us[9] = bfh(cu1.x); us[10] = bfl(cu1.y); us[11] = bfh(cu1.y);
        us[12] = bfl(cu1.z); us[13] = bfh(cu1.z); us[14] = bfl(cu1.w); us[15] = bfh(cu1.w);
        float p = 0.f;
#pragma unroll
        for (int j = 0; j < 16; j++) {
            const float v = us[j] + ud[j];
            p += fmaxf(v, ALPHA_SLOPE * v) * a[j];
        }
        p += __shfl_xor(p, 1, 64);
        p += __shfl_xor(p, 2, 64);        // lanes 0-3: head0 logit, 4-7: head1
        const float logit = p * (1.0f / TEMP);
        const float nm = fmaxf(m, logit);
        const float sc = __expf(m - nm);       // first iter: exp(-inf)=0
        const float wgt = __expf(logit - nm);
        l = l * sc + wgt;
        float wh[16];
        wh[0] = bfl(cw0.x); wh[1] = bfh(cw0.x); wh[2] = bfl(cw0.y); wh[3] = bfh(cw0.y);
        wh[4] = bfl(cw0.z); wh[5] = bfh(cw0.z); wh[6] = bfl(cw0.w); wh[7] = bfh(cw0.w);
        wh[8] = bfl(cw1.x); wh[9] = bfh(cw1.x); wh[10] = bfl(cw1.y); wh[11] = bfh(cw1.y);
        wh[12] = bfl(cw1.z); wh[13] = bfh(cw1.z); wh[14] = bfl(cw1.w); wh[15] = bfh(cw1.w);
#pragma unroll
        for (int j = 0; j < 16; j++) acc[j] = acc[j] * sc + wgt * wh[j];
        m = nm;
    }
    const float inv = 0.5f / (l + 1e-9f);      // ref 1/(sum+1e-9) + head-mean
#pragma unroll
    for (int j = 0; j < 16; j++) {
        const float v = acc[j] * inv;
        acc[j] = v + __shfl_xor(v, 4, 64);     // head0[c] + head1[c]
    }
    if (l8 < 4) {
        float* op = out + (size_t)n * 64 + choff;
#pragma unroll
        for (int i = 0; i < 4; i++) {
            float4 o = make_float4(acc[4 * i], acc[4 * i + 1], acc[4 * i + 2], acc[4 * i + 3]);
            *(float4*)(op + 4 * i) = o;
        }
    }
}

// ---------------------------------------------------------------------------
extern "C" void kernel_launch(void* const* d_in, const int* in_sizes, int n_in,
                              void* d_out, int out_size, void* d_ws, size_t ws_size,
                              hipStream_t stream) {
    const float* x    = (const float*)d_in[0];
    const float* W    = (const float*)d_in[1];
    const float* Wa   = (const float*)d_in[2];
    const float* avec = (const float*)d_in[3];
    const int*   src  = (const int*)d_in[4];
    const int*   dst  = (const int*)d_in[5];
    float* out = (float*)d_out;

    ushort* Zb   = (ushort*)d_ws;                      // 19,200,000 bf16 = 38.4 MB
    ushort* Wctf = Zb + 19200000;                      // 98,304 bf16 (fragment order)
    int*    seg  = (int*)((char*)d_ws + 38596608);     // 50,001 ints

    const int seg_blocks = (N_NODES + 1 + 255) / 256;  // 196
    k_combine <<<ZDIM + seg_blocks, 256, 0, stream>>>(W, Wa, Wctf, dst, seg);
    k_gemm    <<<(N_NODES + 63) / 64, 256, 0, stream>>>(x, Wctf, Zb);
    k_fused   <<<(N_NODES + 31) / 32, 256, 0, stream>>>(Zb, avec, src, seg, out);
}